// Round 1
// baseline (461.440 us; speedup 1.0000x reference)
//
#include <hip/hip_runtime.h>

typedef unsigned short u16;
typedef unsigned int u32;

#define S_LEN 2048
#define FEAT 1024
#define NHEAD 16
#define HDIM 64
#define NBATCH 2
#define NROWS (NBATCH * S_LEN)  // 4096

typedef float f32x4 __attribute__((ext_vector_type(4)));
typedef short s16x8 __attribute__((ext_vector_type(8)));

#define LOG2E 1.4426950408889634f

__device__ inline u16 f2bf(float f) {
  u32 u = __float_as_uint(f);
  return (u16)((u + 0x7fffu + ((u >> 16) & 1u)) >> 16);
}

__device__ inline f32x4 mfma16(s16x8 a, s16x8 b, f32x4 c) {
  return __builtin_amdgcn_mfma_f32_16x16x32_bf16(a, b, c, 0, 0, 0);
}

typedef __attribute__((address_space(1))) void gvoid;
typedef __attribute__((address_space(3))) void lvoid;
__device__ inline void gload_lds16(const void* g, void* l) {
  __builtin_amdgcn_global_load_lds((gvoid*)g, (lvoid*)l, 16, 0, 0);
}

// ---------------- emb table: module's unusual RoPE multiplier ----------------
// emb[p][d]: d<32 -> sin(p*invf[d]), d>=32 -> cos(p*invf[d-32]);
// for p>0: averaged with position (S-p).
__global__ void emb_kernel(float* __restrict__ emb) {
  int i = blockIdx.x * 256 + threadIdx.x;
  if (i >= S_LEN * HDIM) return;
  int p = i >> 6, d = i & 63, j = d & 31;
  // inv_freq = 10000^(-j/32) = 2^(-j/32 * log2(10000))
  float invf = exp2f(-13.287712379549449f * (float)j / 32.0f);
  float a1 = (float)p * invf;
  float v1 = (d < 32) ? sinf(a1) : cosf(a1);
  float e;
  if (p == 0) {
    e = v1;
  } else {
    float a2 = (float)(S_LEN - p) * invf;
    float v2 = (d < 32) ? sinf(a2) : cosf(a2);
    e = 0.5f * (v1 + v2);
  }
  emb[i] = e;
}

// ---------------- f32 -> bf16 convert (vectorized) ----------------
struct us4 { u16 x, y, z, w; };
__global__ void convert_bf16(const float* __restrict__ in, u16* __restrict__ out, int n4) {
  int i = blockIdx.x * 256 + threadIdx.x;
  if (i >= n4) return;
  float4 v = ((const float4*)in)[i];
  us4 o;
  o.x = f2bf(v.x); o.y = f2bf(v.y); o.z = f2bf(v.z); o.w = f2bf(v.w);
  ((us4*)out)[i] = o;
}

// ---------------- weight transpose + convert: Wt[o][i] = bf16(W[i][o]) ----------------
__global__ void wtrans(const float* __restrict__ w0, const float* __restrict__ w1,
                       const float* __restrict__ w2, const float* __restrict__ w3,
                       u16* __restrict__ o0, u16* __restrict__ o1,
                       u16* __restrict__ o2, u16* __restrict__ o3) {
  const float* W = blockIdx.z == 0 ? w0 : blockIdx.z == 1 ? w1 : blockIdx.z == 2 ? w2 : w3;
  u16* O = blockIdx.z == 0 ? o0 : blockIdx.z == 1 ? o1 : blockIdx.z == 2 ? o2 : o3;
  __shared__ float tile[32][33];
  int tx = threadIdx.x & 31, ty = threadIdx.x >> 5;  // 256 threads: 32 x 8
  int bi = blockIdx.x * 32, bo = blockIdx.y * 32;
#pragma unroll
  for (int r = 0; r < 32; r += 8) tile[ty + r][tx] = W[(bi + ty + r) * FEAT + bo + tx];
  __syncthreads();
#pragma unroll
  for (int r = 0; r < 32; r += 8) O[(bo + ty + r) * FEAT + bi + tx] = f2bf(tile[tx][ty + r]);
}

// ---------------- bf16 MFMA GEMM, 128x128 tile, BK=32, fused epilogues ----------------
// A [M][K] bf16 row-major, Bt [N][K] bf16 row-major (= B^T).
// MODE 0: Q proj  -> out bf16 [b,h,s,d], val *= emb[s][d] * 0.125
// MODE 1: K proj  -> out bf16 [b,h,s,d], val *= emb[s][d]
// MODE 2: V proj  -> out bf16 [b,h,d,s]  (transposed for PV B-operand)
// MODE 3: O proj  -> out f32 [row][col]
template <int MODE>
__global__ __launch_bounds__(256) void gemm_bf16(
    const u16* __restrict__ A, const u16* __restrict__ Bt,
    void* __restrict__ Out, const float* __restrict__ emb) {
  __shared__ __align__(16) u16 lA[2][128 * 32];
  __shared__ __align__(16) u16 lB[2][128 * 32];
  const int K = FEAT, N = FEAT;
  int t = threadIdx.x;
  int w = t >> 6, l = t & 63;
  int lr = l & 15, lk = l >> 4;
  int row0 = blockIdx.x * 128, col0 = blockIdx.y * 128;
  int wm = w >> 1, wn = w & 1;

  f32x4 acc[4][4] = {};

  const u16* Asrc = A + (row0 + (t >> 2)) * K + (t & 3) * 8;
  const u16* Bsrc = Bt + (col0 + (t >> 2)) * K + (t & 3) * 8;

  auto stage = [&](int buf, int kt) {
    const u16* a = Asrc + kt * 32;
    const u16* b = Bsrc + kt * 32;
    // LDS dest: wave-uniform base + lane*16B (linear layout, [128 rows][32 k] bf16)
    gload_lds16(a,          &lA[buf][w * 512]);
    gload_lds16(a + 64 * K, &lA[buf][2048 + w * 512]);
    gload_lds16(b,          &lB[buf][w * 512]);
    gload_lds16(b + 64 * K, &lB[buf][2048 + w * 512]);
  };

  stage(0, 0);
  const int NK = K / 32;
  for (int kt = 0; kt < NK; ++kt) {
    __syncthreads();  // drains vmcnt -> staged tile visible; protects dbuf reuse
    if (kt + 1 < NK) stage((kt + 1) & 1, kt + 1);
    int buf = kt & 1;
    s16x8 af[4], bfr[4];
#pragma unroll
    for (int mi = 0; mi < 4; ++mi)
      af[mi] = *(const s16x8*)&lA[buf][(wm * 64 + mi * 16 + lr) * 32 + lk * 8];
#pragma unroll
    for (int ni = 0; ni < 4; ++ni)
      bfr[ni] = *(const s16x8*)&lB[buf][(wn * 64 + ni * 16 + lr) * 32 + lk * 8];
#pragma unroll
    for (int mi = 0; mi < 4; ++mi)
#pragma unroll
      for (int ni = 0; ni < 4; ++ni)
        acc[mi][ni] = mfma16(af[mi], bfr[ni], acc[mi][ni]);
  }

  int rb = row0 + wm * 64 + lk * 4;
  int cb = col0 + wn * 64 + lr;
#pragma unroll
  for (int mi = 0; mi < 4; ++mi)
#pragma unroll
    for (int ni = 0; ni < 4; ++ni)
#pragma unroll
      for (int r = 0; r < 4; ++r) {
        int row = rb + mi * 16 + r;   // C/D layout: row=(l>>4)*4+r, col=l&15 [m89]
        int col = cb + ni * 16;
        float v = acc[mi][ni][r];
        if (MODE == 3) {
          ((float*)Out)[row * N + col] = v;
        } else {
          int b = row >> 11, s = row & (S_LEN - 1);
          int h = col >> 6, d = col & (HDIM - 1);
          if (MODE <= 1) {
            v *= emb[s * HDIM + d];
            if (MODE == 0) v *= 0.125f;  // fold 1/sqrt(HD) into Q
            ((u16*)Out)[(((b << 4) + h) * S_LEN + s) * HDIM + d] = f2bf(v);
          } else {
            ((u16*)Out)[(((b << 4) + h) * HDIM + d) * S_LEN + s] = f2bf(v);
          }
        }
      }
}

// ---------------- flash attention: 4 waves/block, 16 q-rows/wave, KT=64 ----------------
// Q,K: [bh][s][d] bf16 (emb and 1/8 scale pre-applied); Vt: [bh][d][s] bf16.
// AO out: [b][s][h*64+d] bf16.
__global__ __launch_bounds__(256) void attn_kernel(
    const u16* __restrict__ Q, const u16* __restrict__ Kb,
    const u16* __restrict__ Vt, u16* __restrict__ AO) {
  __shared__ __align__(16) u16 lP[4][16 * 64];  // per-wave private P tile [16 q][64 k]
  int t = threadIdx.x, w = t >> 6, l = t & 63;
  int lr = l & 15, lk = l >> 4;
  int bh = blockIdx.x >> 5, qb = blockIdx.x & 31;
  int q0 = qb * 64 + w * 16;
  const u16* Qp = Q + bh * S_LEN * HDIM;
  const u16* Kp = Kb + bh * S_LEN * HDIM;
  const u16* Vp = Vt + bh * HDIM * S_LEN;

  s16x8 qf[2];
#pragma unroll
  for (int ks = 0; ks < 2; ++ks)
    qf[ks] = *(const s16x8*)&Qp[(q0 + lr) * HDIM + lk * 8 + ks * 32];

  f32x4 oacc[4] = {};
  float m[4], lsum[4] = {};
#pragma unroll
  for (int r = 0; r < 4; ++r) m[r] = -3.0e38f;

  int ntiles = qb + 1;  // causal: same trip count for all 4 waves of this block
  for (int kt = 0; kt < ntiles; ++kt) {
    int k0 = kt * 64;
    // QK^T: A=Q (16q x 64d), B^T=K rows (contiguous d) -> scores [16 q][64 k]
    f32x4 sacc[4] = {};
#pragma unroll
    for (int nb = 0; nb < 4; ++nb) {
      const u16* kp = &Kp[(k0 + nb * 16 + lr) * HDIM + lk * 8];
      sacc[nb] = mfma16(qf[0], *(const s16x8*)kp, sacc[nb]);
      sacc[nb] = mfma16(qf[1], *(const s16x8*)(kp + 32), sacc[nb]);
    }
    if (kt == ntiles - 1) {  // only the diagonal tile needs masking
#pragma unroll
      for (int nb = 0; nb < 4; ++nb)
#pragma unroll
        for (int r = 0; r < 4; ++r)
          if (k0 + nb * 16 + lr > q0 + lk * 4 + r) sacc[nb][r] = -3.0e38f;
    }
    // online softmax: row r lives in the lane's 16-lane group; reduce over l&15
    float p[4][4], f[4];
#pragma unroll
    for (int r = 0; r < 4; ++r) {
      float tm = fmaxf(fmaxf(sacc[0][r], sacc[1][r]), fmaxf(sacc[2][r], sacc[3][r]));
#pragma unroll
      for (int msk = 1; msk < 16; msk <<= 1) tm = fmaxf(tm, __shfl_xor(tm, msk, 64));
      float mn = fmaxf(m[r], tm);
      f[r] = exp2f((m[r] - mn) * LOG2E);
      m[r] = mn;
      float rs = 0.f;
#pragma unroll
      for (int nb = 0; nb < 4; ++nb) {
        float pv = exp2f((sacc[nb][r] - mn) * LOG2E);
        p[nb][r] = pv;
        rs += pv;
      }
#pragma unroll
      for (int msk = 1; msk < 16; msk <<= 1) rs += __shfl_xor(rs, msk, 64);
      lsum[r] = lsum[r] * f[r] + rs;
    }
#pragma unroll
    for (int nd = 0; nd < 4; ++nd)
#pragma unroll
      for (int r = 0; r < 4; ++r) oacc[nd][r] *= f[r];
    // P: C-layout -> A-fragment layout via per-wave LDS (wave-internal sync only)
    u16* pl = &lP[w][0];
#pragma unroll
    for (int nb = 0; nb < 4; ++nb)
#pragma unroll
      for (int r = 0; r < 4; ++r)
        pl[(lk * 4 + r) * 64 + nb * 16 + lr] = f2bf(p[nb][r]);
    asm volatile("s_waitcnt lgkmcnt(0)" ::: "memory");
    s16x8 pf0 = *(const s16x8*)&pl[lr * 64 + lk * 8];
    s16x8 pf1 = *(const s16x8*)&pl[lr * 64 + lk * 8 + 32];
    // PV: B^T = V^T rows (contiguous keys)
#pragma unroll
    for (int nd = 0; nd < 4; ++nd) {
      const u16* vp = &Vp[(nd * 16 + lr) * S_LEN + k0 + lk * 8];
      oacc[nd] = mfma16(pf0, *(const s16x8*)vp, oacc[nd]);
      oacc[nd] = mfma16(pf1, *(const s16x8*)(vp + 32), oacc[nd]);
    }
  }
  int b = bh >> 4, h = bh & 15;
#pragma unroll
  for (int r = 0; r < 4; ++r) {
    float inv = 1.0f / lsum[r];
    int qrow = q0 + lk * 4 + r;
    u16* dst = &AO[(b * S_LEN + qrow) * FEAT + h * HDIM];
#pragma unroll
    for (int nd = 0; nd < 4; ++nd) dst[nd * 16 + lr] = f2bf(oacc[nd][r] * inv);
  }
}

extern "C" void kernel_launch(void* const* d_in, const int* in_sizes, int n_in,
                              void* d_out, int out_size, void* d_ws, size_t ws_size,
                              hipStream_t stream) {
  const float* kv = (const float*)d_in[0];
  const float* q  = (const float*)d_in[1];
  const float* Wq = (const float*)d_in[2];
  const float* Wk = (const float*)d_in[3];
  const float* Wv = (const float*)d_in[4];
  const float* Wo = (const float*)d_in[5];
  // d_in[6] = causal mask (tril) -- known statically, unused.

  // workspace layout (~56.5 MB)
  float* emb = (float*)d_ws;                              // 2048*64 f32 = 512 KB
  u16* qbf  = (u16*)((char*)d_ws + S_LEN * HDIM * 4);
  u16* kvbf = qbf + NROWS * FEAT;                         // 8 MB each
  u16* WqT  = kvbf + NROWS * FEAT;
  u16* WkT  = WqT + FEAT * FEAT;                          // 2 MB each
  u16* WvT  = WkT + FEAT * FEAT;
  u16* WoT  = WvT + FEAT * FEAT;
  u16* Qb   = WoT + FEAT * FEAT;                          // 8 MB each
  u16* Kx   = Qb + NROWS * FEAT;
  u16* Vx   = Kx + NROWS * FEAT;
  u16* AO   = Vx + NROWS * FEAT;

  emb_kernel<<<(S_LEN * HDIM + 255) / 256, 256, 0, stream>>>(emb);
  convert_bf16<<<(NROWS * FEAT / 4 + 255) / 256, 256, 0, stream>>>(q, qbf, NROWS * FEAT / 4);
  convert_bf16<<<(NROWS * FEAT / 4 + 255) / 256, 256, 0, stream>>>(kv, kvbf, NROWS * FEAT / 4);
  wtrans<<<dim3(32, 32, 4), 256, 0, stream>>>(Wq, Wk, Wv, Wo, WqT, WkT, WvT, WoT);

  dim3 gg(NROWS / 128, FEAT / 128);  // (32, 8)
  gemm_bf16<0><<<gg, 256, 0, stream>>>(qbf, WqT, Qb, emb);
  gemm_bf16<1><<<gg, 256, 0, stream>>>(kvbf, WkT, Kx, emb);
  gemm_bf16<2><<<gg, 256, 0, stream>>>(kvbf, WvT, Vx, emb);

  attn_kernel<<<NBATCH * NHEAD * (S_LEN / 64), 256, 0, stream>>>(Qb, Kx, Vx, AO);

  gemm_bf16<3><<<gg, 256, 0, stream>>>(AO, WoT, d_out, emb);
}

// Round 2
// 244.379 us; speedup vs baseline: 1.8882x; 1.8882x over previous
//
#include <hip/hip_runtime.h>

typedef unsigned short u16;
typedef unsigned int u32;

#define S_LEN 2048
#define FEAT 1024
#define NHEAD 16
#define HDIM 64
#define NBATCH 2
#define NROWS (NBATCH * S_LEN)  // 4096

typedef float f32x4 __attribute__((ext_vector_type(4)));
typedef short s16x8 __attribute__((ext_vector_type(8)));
typedef u32 u32x2 __attribute__((ext_vector_type(2)));

#define LOG2E 1.4426950408889634f

__device__ inline u16 f2bf(float f) {
  u32 u = __float_as_uint(f);
  return (u16)((u + 0x7fffu + ((u >> 16) & 1u)) >> 16);
}

__device__ inline u32 cvt_pk_bf16(float lo, float hi) {
  u32 r;
  asm("v_cvt_pk_bf16_f32 %0, %1, %2" : "=v"(r) : "v"(lo), "v"(hi));
  return r;
}

__device__ inline float fexp2(float x) { return __builtin_amdgcn_exp2f(x); }

__device__ inline f32x4 mfma16(s16x8 a, s16x8 b, f32x4 c) {
  return __builtin_amdgcn_mfma_f32_16x16x32_bf16(a, b, c, 0, 0, 0);
}

typedef __attribute__((address_space(1))) void gvoid;
typedef __attribute__((address_space(3))) void lvoid;
__device__ inline void gload_lds16(const void* g, void* l) {
  __builtin_amdgcn_global_load_lds((gvoid*)g, (lvoid*)l, 16, 0, 0);
}

// ---------------- emb table: module's unusual RoPE multiplier ----------------
__global__ void emb_kernel(float* __restrict__ emb) {
  int i = blockIdx.x * 256 + threadIdx.x;
  if (i >= S_LEN * HDIM) return;
  int p = i >> 6, d = i & 63, j = d & 31;
  float invf = exp2f(-13.287712379549449f * (float)j / 32.0f);
  float a1 = (float)p * invf;
  float v1 = (d < 32) ? sinf(a1) : cosf(a1);
  float e;
  if (p == 0) {
    e = v1;
  } else {
    float a2 = (float)(S_LEN - p) * invf;
    float v2 = (d < 32) ? sinf(a2) : cosf(a2);
    e = 0.5f * (v1 + v2);
  }
  emb[i] = e;
}

// ---------------- f32 -> bf16 convert (vectorized) ----------------
struct us4 { u16 x, y, z, w; };
__global__ void convert_bf16(const float* __restrict__ in, u16* __restrict__ out, int n4) {
  int i = blockIdx.x * 256 + threadIdx.x;
  if (i >= n4) return;
  float4 v = ((const float4*)in)[i];
  us4 o;
  o.x = f2bf(v.x); o.y = f2bf(v.y); o.z = f2bf(v.z); o.w = f2bf(v.w);
  ((us4*)out)[i] = o;
}

// ---------------- weight transpose + convert: Wt[o][i] = bf16(W[i][o]) ----------------
__global__ void wtrans(const float* __restrict__ w0, const float* __restrict__ w1,
                       const float* __restrict__ w2, const float* __restrict__ w3,
                       u16* __restrict__ o0, u16* __restrict__ o1,
                       u16* __restrict__ o2, u16* __restrict__ o3) {
  const float* W = blockIdx.z == 0 ? w0 : blockIdx.z == 1 ? w1 : blockIdx.z == 2 ? w2 : w3;
  u16* O = blockIdx.z == 0 ? o0 : blockIdx.z == 1 ? o1 : blockIdx.z == 2 ? o2 : o3;
  __shared__ float tile[32][33];
  int tx = threadIdx.x & 31, ty = threadIdx.x >> 5;  // 256 threads: 32 x 8
  int bi = blockIdx.x * 32, bo = blockIdx.y * 32;
#pragma unroll
  for (int r = 0; r < 32; r += 8) tile[ty + r][tx] = W[(bi + ty + r) * FEAT + bo + tx];
  __syncthreads();
#pragma unroll
  for (int r = 0; r < 32; r += 8) O[(bo + ty + r) * FEAT + bi + tx] = f2bf(tile[tx][ty + r]);
}

// ---------------- bf16 MFMA GEMM, 128x128 tile, BK=32, fused epilogues ----------------
// A [M][K] bf16 row-major, Bt [N][K] bf16 row-major (= B^T).
// MODE 0: Q proj  -> out bf16 [b,h,s,d], val *= emb[s][d] * 0.125
// MODE 1: K proj  -> out bf16 [b,h,s,d], val *= emb[s][d]
// MODE 2: V proj  -> out bf16 [b,h,d,s]  (transposed for PV A-operand)
// MODE 3: O proj  -> out f32 [row][col]
template <int MODE>
__global__ __launch_bounds__(256) void gemm_bf16(
    const u16* __restrict__ A, const u16* __restrict__ Bt,
    void* __restrict__ Out, const float* __restrict__ emb) {
  __shared__ __align__(16) u16 lA[2][128 * 32];
  __shared__ __align__(16) u16 lB[2][128 * 32];
  const int K = FEAT, N = FEAT;
  int t = threadIdx.x;
  int w = t >> 6, l = t & 63;
  int lr = l & 15, lk = l >> 4;
  int row0 = blockIdx.x * 128, col0 = blockIdx.y * 128;
  int wm = w >> 1, wn = w & 1;

  f32x4 acc[4][4] = {};

  const u16* Asrc = A + (row0 + (t >> 2)) * K + (t & 3) * 8;
  const u16* Bsrc = Bt + (col0 + (t >> 2)) * K + (t & 3) * 8;

  auto stage = [&](int buf, int kt) {
    const u16* a = Asrc + kt * 32;
    const u16* b = Bsrc + kt * 32;
    gload_lds16(a,          &lA[buf][w * 512]);
    gload_lds16(a + 64 * K, &lA[buf][2048 + w * 512]);
    gload_lds16(b,          &lB[buf][w * 512]);
    gload_lds16(b + 64 * K, &lB[buf][2048 + w * 512]);
  };

  stage(0, 0);
  const int NK = K / 32;
  for (int kt = 0; kt < NK; ++kt) {
    __syncthreads();
    if (kt + 1 < NK) stage((kt + 1) & 1, kt + 1);
    int buf = kt & 1;
    s16x8 af[4], bfr[4];
#pragma unroll
    for (int mi = 0; mi < 4; ++mi)
      af[mi] = *(const s16x8*)&lA[buf][(wm * 64 + mi * 16 + lr) * 32 + lk * 8];
#pragma unroll
    for (int ni = 0; ni < 4; ++ni)
      bfr[ni] = *(const s16x8*)&lB[buf][(wn * 64 + ni * 16 + lr) * 32 + lk * 8];
#pragma unroll
    for (int mi = 0; mi < 4; ++mi)
#pragma unroll
      for (int ni = 0; ni < 4; ++ni)
        acc[mi][ni] = mfma16(af[mi], bfr[ni], acc[mi][ni]);
  }

  int rb = row0 + wm * 64 + lk * 4;
  int cb = col0 + wn * 64 + lr;
#pragma unroll
  for (int mi = 0; mi < 4; ++mi)
#pragma unroll
    for (int ni = 0; ni < 4; ++ni)
#pragma unroll
      for (int r = 0; r < 4; ++r) {
        int row = rb + mi * 16 + r;   // C/D layout: row=(l>>4)*4+r, col=l&15 [m89]
        int col = cb + ni * 16;
        float v = acc[mi][ni][r];
        if (MODE == 3) {
          ((float*)Out)[row * N + col] = v;
        } else {
          int b = row >> 11, s = row & (S_LEN - 1);
          int h = col >> 6, d = col & (HDIM - 1);
          if (MODE <= 1) {
            v *= emb[s * HDIM + d];
            if (MODE == 0) v *= 0.125f;  // fold 1/sqrt(HD) into Q
            ((u16*)Out)[(((b << 4) + h) * S_LEN + s) * HDIM + d] = f2bf(v);
          } else {
            ((u16*)Out)[(((b << 4) + h) * HDIM + d) * S_LEN + s] = f2bf(v);
          }
        }
      }
}

// ---------------- flash attention v2: swapped-QK^T, balanced pairs ----------------
// Q,K: [bh][s][d] bf16 (emb & 1/8 pre-applied on Q); Vt: [bh][d][s] bf16.
// Wave-task = 16 q-rows. Each wave processes q-tile pair (pr, 127-pr): exactly
// 33 key-tiles of 64 keys -> perfect causal balance. Waves independent (no
// block barrier); per-wave double-buffered XOR-swizzled LDS for P transpose.
__global__ __launch_bounds__(256, 2) void attn_kernel(
    const u16* __restrict__ Q, const u16* __restrict__ Kb,
    const u16* __restrict__ Vt, u16* __restrict__ AO) {
  __shared__ __align__(16) u16 lP[4][2][16 * 64];  // 16 KB
  int t = threadIdx.x, w = t >> 6, l = t & 63;
  int lr = l & 15, lk = l >> 4;
  int task = blockIdx.x * 4 + w;       // 2048 wave-tasks
  int bh = task >> 6, pr = task & 63;  // 64 pairs per bh
  const u16* Qp = Q + bh * (S_LEN * HDIM);
  const u16* Kp = Kb + bh * (S_LEN * HDIM);
  const u16* Vp = Vt + bh * (HDIM * S_LEN);
  int b = bh >> 4, h = bh & 15;

  for (int half = 0; half < 2; ++half) {
    int qt = half ? (127 - pr) : pr;
    int q0 = qt * 16;
    int qrow = q0 + lr;  // this lane's q-column

    // B-operand fragment: Q[q=lr][d=lk*8+j (+ks*32)]
    s16x8 qf0 = *(const s16x8*)&Qp[qrow * HDIM + lk * 8];
    s16x8 qf1 = *(const s16x8*)&Qp[qrow * HDIM + lk * 8 + 32];

    f32x4 oacc[4] = {};
    float m = -3.0e38f, lsum = 0.f;
    int ntiles = qt / 4 + 1;

    // preload K tile 0: A-frag rows = keys, k = d
    s16x8 kf[4][2], kn[4][2];
#pragma unroll
    for (int nb = 0; nb < 4; ++nb) {
      const u16* kp = &Kp[(nb * 16 + lr) * HDIM + lk * 8];
      kf[nb][0] = *(const s16x8*)kp;
      kf[nb][1] = *(const s16x8*)(kp + 32);
    }

    for (int kt = 0; kt < ntiles; ++kt) {
      // prefetch next K tile early (hides under QK + softmax)
      bool more = (kt + 1 < ntiles);
      if (more) {
        const u16* kp = &Kp[((kt + 1) * 64 + lr) * HDIM + lk * 8];
#pragma unroll
        for (int nb = 0; nb < 4; ++nb) {
          kn[nb][0] = *(const s16x8*)(kp + nb * 16 * HDIM);
          kn[nb][1] = *(const s16x8*)(kp + nb * 16 * HDIM + 32);
        }
      }
      // V tile loads (independent of softmax; issue early)
      s16x8 vf[4][2];
#pragma unroll
      for (int nd = 0; nd < 4; ++nd) {
        const u16* vp = &Vp[(nd * 16 + lr) * S_LEN + kt * 64 + lk * 8];
        vf[nd][0] = *(const s16x8*)vp;
        vf[nd][1] = *(const s16x8*)(vp + 32);
      }

      // QK^T swapped: C[key][q]; lane holds 16 scores (keys) for q=lr
      f32x4 sacc[4] = {};
#pragma unroll
      for (int nb = 0; nb < 4; ++nb) {
        sacc[nb] = mfma16(kf[nb][0], qf0, sacc[nb]);
        sacc[nb] = mfma16(kf[nb][1], qf1, sacc[nb]);
      }

      if (kt == ntiles - 1) {  // only diagonal tile masks
#pragma unroll
        for (int nb = 0; nb < 4; ++nb)
#pragma unroll
          for (int r = 0; r < 4; ++r)
            if (kt * 64 + nb * 16 + lk * 4 + r > qrow) sacc[nb][r] = -3.0e38f;
      }

      // online softmax: in-register reduce + 2 shfl over lk lanes
      float tm = sacc[0][0];
#pragma unroll
      for (int nb = 0; nb < 4; ++nb)
#pragma unroll
        for (int r = 0; r < 4; ++r) tm = fmaxf(tm, sacc[nb][r]);
      tm = fmaxf(tm, __shfl_xor(tm, 16, 64));
      tm = fmaxf(tm, __shfl_xor(tm, 32, 64));
      float mn = fmaxf(m, tm);
      float fs = fexp2((m - mn) * LOG2E);
      m = mn;
      float rs = 0.f;
      float p[4][4];
#pragma unroll
      for (int nb = 0; nb < 4; ++nb)
#pragma unroll
        for (int r = 0; r < 4; ++r) {
          float pv = fexp2((sacc[nb][r] - mn) * LOG2E);
          p[nb][r] = pv;
          rs += pv;
        }
      rs += __shfl_xor(rs, 16, 64);
      rs += __shfl_xor(rs, 32, 64);
      lsum = lsum * fs + rs;
#pragma unroll
      for (int nd = 0; nd < 4; ++nd)
#pragma unroll
        for (int r = 0; r < 4; ++r) oacc[nd][r] *= fs;

      // P^T -> B-frag layout via per-wave LDS, XOR-swizzled (G4: byte ^= (q&7)<<4)
      char* plb = (char*)&lP[w][kt & 1][0];
#pragma unroll
      for (int nb = 0; nb < 4; ++nb) {
        u32x2 pw;
        pw.x = cvt_pk_bf16(p[nb][0], p[nb][1]);
        pw.y = cvt_pk_bf16(p[nb][2], p[nb][3]);
        int off = (lr * 128 + nb * 32 + lk * 8) ^ ((lr & 7) << 4);
        *(u32x2*)(plb + off) = pw;
      }
      asm volatile("s_waitcnt lgkmcnt(0)" ::: "memory");
      __builtin_amdgcn_sched_barrier(0);
      s16x8 pf0 = *(const s16x8*)(plb + ((lr * 128 + lk * 16) ^ ((lr & 7) << 4)));
      s16x8 pf1 = *(const s16x8*)(plb + ((lr * 128 + 64 + lk * 16) ^ ((lr & 7) << 4)));

      // PV: C[d][q] += V^T[d][k] * P^T[k][q]
#pragma unroll
      for (int nd = 0; nd < 4; ++nd) {
        oacc[nd] = mfma16(vf[nd][0], pf0, oacc[nd]);
        oacc[nd] = mfma16(vf[nd][1], pf1, oacc[nd]);
      }

      if (more) {
#pragma unroll
        for (int nb = 0; nb < 4; ++nb) {
          kf[nb][0] = kn[nb][0];
          kf[nb][1] = kn[nb][1];
        }
      }
    }

    // epilogue: lane holds out[d = nd*16+lk*4+r][q=qrow]; 8B stores
    float inv = 1.0f / lsum;
    u16* dst = &AO[(b * S_LEN + qrow) * FEAT + h * HDIM + lk * 4];
#pragma unroll
    for (int nd = 0; nd < 4; ++nd) {
      us4 o;
      o.x = f2bf(oacc[nd][0] * inv);
      o.y = f2bf(oacc[nd][1] * inv);
      o.z = f2bf(oacc[nd][2] * inv);
      o.w = f2bf(oacc[nd][3] * inv);
      *(us4*)(dst + nd * 16) = o;
    }
  }
}

extern "C" void kernel_launch(void* const* d_in, const int* in_sizes, int n_in,
                              void* d_out, int out_size, void* d_ws, size_t ws_size,
                              hipStream_t stream) {
  const float* kv = (const float*)d_in[0];
  const float* q  = (const float*)d_in[1];
  const float* Wq = (const float*)d_in[2];
  const float* Wk = (const float*)d_in[3];
  const float* Wv = (const float*)d_in[4];
  const float* Wo = (const float*)d_in[5];

  float* emb = (float*)d_ws;                              // 512 KB
  u16* qbf  = (u16*)((char*)d_ws + S_LEN * HDIM * 4);
  u16* kvbf = qbf + NROWS * FEAT;                         // 8 MB each
  u16* WqT  = kvbf + NROWS * FEAT;
  u16* WkT  = WqT + FEAT * FEAT;                          // 2 MB each
  u16* WvT  = WkT + FEAT * FEAT;
  u16* WoT  = WvT + FEAT * FEAT;
  u16* Qb   = WoT + FEAT * FEAT;                          // 8 MB each
  u16* Kx   = Qb + NROWS * FEAT;
  u16* Vx   = Kx + NROWS * FEAT;
  u16* AO   = Vx + NROWS * FEAT;

  emb_kernel<<<(S_LEN * HDIM + 255) / 256, 256, 0, stream>>>(emb);
  convert_bf16<<<(NROWS * FEAT / 4 + 255) / 256, 256, 0, stream>>>(q, qbf, NROWS * FEAT / 4);
  convert_bf16<<<(NROWS * FEAT / 4 + 255) / 256, 256, 0, stream>>>(kv, kvbf, NROWS * FEAT / 4);
  wtrans<<<dim3(32, 32, 4), 256, 0, stream>>>(Wq, Wk, Wv, Wo, WqT, WkT, WvT, WoT);

  dim3 gg(NROWS / 128, FEAT / 128);  // (32, 8)
  gemm_bf16<0><<<gg, 256, 0, stream>>>(qbf, WqT, Qb, emb);
  gemm_bf16<1><<<gg, 256, 0, stream>>>(kvbf, WkT, Kx, emb);
  gemm_bf16<2><<<gg, 256, 0, stream>>>(kvbf, WvT, Vx, emb);

  attn_kernel<<<512, 256, 0, stream>>>(Qb, Kx, Vx, AO);

  gemm_bf16<3><<<gg, 256, 0, stream>>>(AO, WoT, d_out, emb);
}

// Round 3
// 179.980 us; speedup vs baseline: 2.5638x; 1.3578x over previous
//
#include <hip/hip_runtime.h>

typedef unsigned short u16;
typedef unsigned int u32;

#define S_LEN 2048
#define FEAT 1024
#define NHEAD 16
#define HDIM 64
#define NBATCH 2
#define NROWS (NBATCH * S_LEN)  // 4096

typedef float f32x4 __attribute__((ext_vector_type(4)));
typedef short s16x8 __attribute__((ext_vector_type(8)));
typedef u32 u32x2 __attribute__((ext_vector_type(2)));

#define LOG2E 1.4426950408889634f

__device__ inline u16 f2bf(float f) {
  u32 u = __float_as_uint(f);
  return (u16)((u + 0x7fffu + ((u >> 16) & 1u)) >> 16);
}

__device__ inline u32 cvt_pk_bf16(float lo, float hi) {
  u32 r;
  asm("v_cvt_pk_bf16_f32 %0, %1, %2" : "=v"(r) : "v"(lo), "v"(hi));
  return r;
}

__device__ inline float fexp2(float x) { return __builtin_amdgcn_exp2f(x); }

__device__ inline f32x4 mfma16(s16x8 a, s16x8 b, f32x4 c) {
  return __builtin_amdgcn_mfma_f32_16x16x32_bf16(a, b, c, 0, 0, 0);
}

typedef __attribute__((address_space(1))) void gvoid;
typedef __attribute__((address_space(3))) void lvoid;
__device__ inline void gload_lds16(const void* g, void* l) {
  __builtin_amdgcn_global_load_lds((gvoid*)g, (lvoid*)l, 16, 0, 0);
}

// ---------------- emb table: module's unusual RoPE multiplier ----------------
__global__ void emb_kernel(float* __restrict__ emb) {
  int i = blockIdx.x * 256 + threadIdx.x;
  if (i >= S_LEN * HDIM) return;
  int p = i >> 6, d = i & 63, j = d & 31;
  float invf = exp2f(-13.287712379549449f * (float)j / 32.0f);
  float a1 = (float)p * invf;
  float v1 = (d < 32) ? sinf(a1) : cosf(a1);
  float e;
  if (p == 0) {
    e = v1;
  } else {
    float a2 = (float)(S_LEN - p) * invf;
    float v2 = (d < 32) ? sinf(a2) : cosf(a2);
    e = 0.5f * (v1 + v2);
  }
  emb[i] = e;
}

// ---------------- f32 -> bf16 convert (vectorized) ----------------
struct us4 { u16 x, y, z, w; };
__global__ void convert_bf16(const float* __restrict__ in, u16* __restrict__ out, int n4) {
  int i = blockIdx.x * 256 + threadIdx.x;
  if (i >= n4) return;
  float4 v = ((const float4*)in)[i];
  us4 o;
  o.x = f2bf(v.x); o.y = f2bf(v.y); o.z = f2bf(v.z); o.w = f2bf(v.w);
  ((us4*)out)[i] = o;
}

// ---------------- weight transpose + convert: Wt[o][i] = bf16(W[i][o]) ----------------
__global__ void wtrans(const float* __restrict__ w0, const float* __restrict__ w1,
                       const float* __restrict__ w2, const float* __restrict__ w3,
                       u16* __restrict__ o0, u16* __restrict__ o1,
                       u16* __restrict__ o2, u16* __restrict__ o3) {
  const float* W = blockIdx.z == 0 ? w0 : blockIdx.z == 1 ? w1 : blockIdx.z == 2 ? w2 : w3;
  u16* O = blockIdx.z == 0 ? o0 : blockIdx.z == 1 ? o1 : blockIdx.z == 2 ? o2 : o3;
  __shared__ float tile[32][33];
  int tx = threadIdx.x & 31, ty = threadIdx.x >> 5;  // 256 threads: 32 x 8
  int bi = blockIdx.x * 32, bo = blockIdx.y * 32;
#pragma unroll
  for (int r = 0; r < 32; r += 8) tile[ty + r][tx] = W[(bi + ty + r) * FEAT + bo + tx];
  __syncthreads();
#pragma unroll
  for (int r = 0; r < 32; r += 8) O[(bo + ty + r) * FEAT + bi + tx] = f2bf(tile[tx][ty + r]);
}

// ---------------- bf16 MFMA GEMM, 128x128 tile, BK=32, fused epilogues ----------------
template <int MODE>
__global__ __launch_bounds__(256) void gemm_bf16(
    const u16* __restrict__ A, const u16* __restrict__ Bt,
    void* __restrict__ Out, const float* __restrict__ emb) {
  __shared__ __align__(16) u16 lA[2][128 * 32];
  __shared__ __align__(16) u16 lB[2][128 * 32];
  const int K = FEAT, N = FEAT;
  int t = threadIdx.x;
  int w = t >> 6, l = t & 63;
  int lr = l & 15, lk = l >> 4;
  int row0 = blockIdx.x * 128, col0 = blockIdx.y * 128;
  int wm = w >> 1, wn = w & 1;

  f32x4 acc[4][4] = {};

  const u16* Asrc = A + (row0 + (t >> 2)) * K + (t & 3) * 8;
  const u16* Bsrc = Bt + (col0 + (t >> 2)) * K + (t & 3) * 8;

  auto stage = [&](int buf, int kt) {
    const u16* a = Asrc + kt * 32;
    const u16* b = Bsrc + kt * 32;
    gload_lds16(a,          &lA[buf][w * 512]);
    gload_lds16(a + 64 * K, &lA[buf][2048 + w * 512]);
    gload_lds16(b,          &lB[buf][w * 512]);
    gload_lds16(b + 64 * K, &lB[buf][2048 + w * 512]);
  };

  stage(0, 0);
  const int NK = K / 32;
  for (int kt = 0; kt < NK; ++kt) {
    __syncthreads();
    if (kt + 1 < NK) stage((kt + 1) & 1, kt + 1);
    int buf = kt & 1;
    s16x8 af[4], bfr[4];
#pragma unroll
    for (int mi = 0; mi < 4; ++mi)
      af[mi] = *(const s16x8*)&lA[buf][(wm * 64 + mi * 16 + lr) * 32 + lk * 8];
#pragma unroll
    for (int ni = 0; ni < 4; ++ni)
      bfr[ni] = *(const s16x8*)&lB[buf][(wn * 64 + ni * 16 + lr) * 32 + lk * 8];
#pragma unroll
    for (int mi = 0; mi < 4; ++mi)
#pragma unroll
      for (int ni = 0; ni < 4; ++ni)
        acc[mi][ni] = mfma16(af[mi], bfr[ni], acc[mi][ni]);
  }

  int rb = row0 + wm * 64 + lk * 4;
  int cb = col0 + wn * 64 + lr;
#pragma unroll
  for (int mi = 0; mi < 4; ++mi)
#pragma unroll
    for (int ni = 0; ni < 4; ++ni)
#pragma unroll
      for (int r = 0; r < 4; ++r) {
        int row = rb + mi * 16 + r;   // C/D layout: row=(l>>4)*4+r, col=l&15 [m89]
        int col = cb + ni * 16;
        float v = acc[mi][ni][r];
        if (MODE == 3) {
          ((float*)Out)[row * N + col] = v;
        } else {
          int b = row >> 11, s = row & (S_LEN - 1);
          int h = col >> 6, d = col & (HDIM - 1);
          if (MODE <= 1) {
            v *= emb[s * HDIM + d];
            if (MODE == 0) v *= 0.125f;  // fold 1/sqrt(HD) into Q
            ((u16*)Out)[(((b << 4) + h) * S_LEN + s) * HDIM + d] = f2bf(v);
          } else {
            ((u16*)Out)[(((b << 4) + h) * HDIM + d) * S_LEN + s] = f2bf(v);
          }
        }
      }
}

// ---------------- flash attention v3: block-shared LDS K/V, dual-half pairs ----------------
// Q,K: [bh][s][d] bf16 (emb & 1/8 on Q); Vt: [bh][d][s] bf16. AO: [b][s][h*64+d] bf16.
// Block = pair of 64-row q-blocks (qbp, 31-qbp), 4 waves x 16 rows each half.
// Loop kt=0..(32-qbp-1); both halves active while kt<=qbp -> uniform 33 half-tile
// units per block. K/V staged in LDS via global_load_lds, double-buffered,
// XOR-swizzle (byte ^= (row&7)<<4) applied via pre-swizzled global source (rule #21).
__global__ __launch_bounds__(256, 2) void attn_kernel(
    const u16* __restrict__ Q, const u16* __restrict__ Kb,
    const u16* __restrict__ Vt, u16* __restrict__ AO) {
  __shared__ __align__(16) u16 lK[2][64 * 64];  // 16 KB: [buf][key][d] (swizzled)
  __shared__ __align__(16) u16 lV[2][64 * 64];  // 16 KB: [buf][d][key] (swizzled)
  __shared__ __align__(16) u16 lP[4][16 * 64];  // 8 KB: per-wave P^T (swizzled)

  int t = threadIdx.x, w = t >> 6, l = t & 63;
  int lr = l & 15, lk = l >> 4;
  int bid = blockIdx.x;
  int bh = bid >> 4, qbp = bid & 15;      // 32 bh x 16 pairs
  int qtA = qbp, qtB = 31 - qbp;          // 64-row q-block indices
  int ntA = qtA + 1, ntB = qtB + 1;       // 64-key tiles per half (ntA < ntB)
  const u16* Qp = Q + bh * (S_LEN * HDIM);
  const char* Kc = (const char*)(Kb + bh * (S_LEN * HDIM));
  const char* Vc = (const char*)(Vt + bh * (HDIM * S_LEN));
  int b = bh >> 4, h = bh & 15;
  int sw = (lr & 7) << 4;

  // staging geometry: thread covers LDS byte P0 = w*1024 + l*16 (+4096 round 2)
  int P0 = w * 1024 + l * 16;
  int row0 = P0 >> 7;
  int srcK0 = P0 ^ ((row0 & 7) << 4);                    // K tile contiguous 8KB
  int srcV0 = row0 * 4096 + ((P0 & 127) ^ ((row0 & 7) << 4));  // V rows strided 4KB

  auto stage = [&](int buf, int kt) {
    gload_lds16(Kc + kt * 8192 + srcK0,          (char*)&lK[buf][0] + w * 1024);
    gload_lds16(Kc + kt * 8192 + srcK0 + 4096,   (char*)&lK[buf][0] + w * 1024 + 4096);
    gload_lds16(Vc + kt * 128 + srcV0,           (char*)&lV[buf][0] + w * 1024);
    gload_lds16(Vc + kt * 128 + srcV0 + 131072,  (char*)&lV[buf][0] + w * 1024 + 4096);
  };

  // Q fragments (B-operand): lane lr = q-col, lk*8 = d-slice
  int qrowA = qtA * 64 + w * 16 + lr;
  int qrowB = qtB * 64 + w * 16 + lr;
  s16x8 qA0 = *(const s16x8*)&Qp[qrowA * HDIM + lk * 8];
  s16x8 qA1 = *(const s16x8*)&Qp[qrowA * HDIM + lk * 8 + 32];
  s16x8 qB0 = *(const s16x8*)&Qp[qrowB * HDIM + lk * 8];
  s16x8 qB1 = *(const s16x8*)&Qp[qrowB * HDIM + lk * 8 + 32];

  f32x4 oA[4] = {}, oB[4] = {};
  float mA = -3.0e38f, lsA = 0.f, mB = -3.0e38f, lsB = 0.f;
  char* plb = (char*)&lP[w][0];

  // softmax + P-transpose + PV for one half on the current tile
  auto half_sm_pv = [&](f32x4 (&sacc)[4], f32x4 (&oacc)[4], float& m, float& ls,
                        int qrow, bool diag, int kt, const s16x8 (&vf)[4][2]) {
    if (diag) {
#pragma unroll
      for (int nb = 0; nb < 4; ++nb)
#pragma unroll
        for (int r = 0; r < 4; ++r)
          if (kt * 64 + nb * 16 + lk * 4 + r > qrow) sacc[nb][r] = -3.0e38f;
    }
    float tm = sacc[0][0];
#pragma unroll
    for (int nb = 0; nb < 4; ++nb)
#pragma unroll
      for (int r = 0; r < 4; ++r) tm = fmaxf(tm, sacc[nb][r]);
    tm = fmaxf(tm, __shfl_xor(tm, 16, 64));
    tm = fmaxf(tm, __shfl_xor(tm, 32, 64));
    // defer-max (T13, THR=8): skip O/lsum rescale when max growth small
    if (!__all(tm <= m + 8.0f)) {
      float mn = fmaxf(m, tm);
      float fs = fexp2((m - mn) * LOG2E);
      m = mn;
      ls *= fs;
#pragma unroll
      for (int nd = 0; nd < 4; ++nd)
#pragma unroll
        for (int r = 0; r < 4; ++r) oacc[nd][r] *= fs;
    }
    float rs = 0.f;
    float p[4][4];
#pragma unroll
    for (int nb = 0; nb < 4; ++nb)
#pragma unroll
      for (int r = 0; r < 4; ++r) {
        float pv = fexp2((sacc[nb][r] - m) * LOG2E);
        p[nb][r] = pv;
        rs += pv;
      }
    rs += __shfl_xor(rs, 16, 64);
    rs += __shfl_xor(rs, 32, 64);
    ls += rs;
    // P^T -> B-frag layout via per-wave LDS (XOR swizzle; single buffer is safe:
    // per-wave DS ops are in-order and accesses alias)
#pragma unroll
    for (int nb = 0; nb < 4; ++nb) {
      u32x2 pw;
      pw.x = cvt_pk_bf16(p[nb][0], p[nb][1]);
      pw.y = cvt_pk_bf16(p[nb][2], p[nb][3]);
      int off = (lr * 128 + nb * 32 + lk * 8) ^ sw;
      *(u32x2*)(plb + off) = pw;
    }
    asm volatile("s_waitcnt lgkmcnt(0)" ::: "memory");
    __builtin_amdgcn_sched_barrier(0);
    s16x8 pf0 = *(const s16x8*)(plb + ((lr * 128 + lk * 16) ^ sw));
    s16x8 pf1 = *(const s16x8*)(plb + ((lr * 128 + 64 + lk * 16) ^ sw));
    __builtin_amdgcn_s_setprio(1);
#pragma unroll
    for (int nd = 0; nd < 4; ++nd) {
      oacc[nd] = mfma16(vf[nd][0], pf0, oacc[nd]);
      oacc[nd] = mfma16(vf[nd][1], pf1, oacc[nd]);
    }
    __builtin_amdgcn_s_setprio(0);
  };

  stage(0, 0);
  for (int kt = 0; kt < ntB; ++kt) {
    __syncthreads();  // staged tile kt visible; prev buf free
    if (kt + 1 < ntB) stage((kt + 1) & 1, kt + 1);
    int buf = kt & 1;
    const char* kb = (const char*)&lK[buf][0];
    const char* vb = (const char*)&lV[buf][0];
    bool dual = (kt < ntA);

    // V fragments early (latency hides under QK + softmax)
    s16x8 vf[4][2];
#pragma unroll
    for (int nd = 0; nd < 4; ++nd)
#pragma unroll
      for (int ks = 0; ks < 2; ++ks)
        vf[nd][ks] = *(const s16x8*)(vb + nd * 2048 + lr * 128 + ((lk * 16 + ks * 64) ^ sw));

    // QK^T swapped (C[key][q]); K-frags read once, feed both halves
    f32x4 sA[4] = {}, sB[4] = {};
    __builtin_amdgcn_s_setprio(1);
#pragma unroll
    for (int nb = 0; nb < 4; ++nb)
#pragma unroll
      for (int ks = 0; ks < 2; ++ks) {
        s16x8 kf = *(const s16x8*)(kb + nb * 2048 + lr * 128 + ((lk * 16 + ks * 64) ^ sw));
        sB[nb] = mfma16(kf, ks ? qB1 : qB0, sB[nb]);
        if (dual) sA[nb] = mfma16(kf, ks ? qA1 : qA0, sA[nb]);
      }
    __builtin_amdgcn_s_setprio(0);

    half_sm_pv(sB, oB, mB, lsB, qrowB, kt == ntB - 1, kt, vf);
    if (dual) half_sm_pv(sA, oA, mA, lsA, qrowA, kt == ntA - 1, kt, vf);
  }

  // epilogue: lane holds out[d = nd*16+lk*4+r][q=qrow]
#pragma unroll
  for (int half = 0; half < 2; ++half) {
    f32x4* oacc = half ? oB : oA;
    float inv = 1.0f / (half ? lsB : lsA);
    int qrow = half ? qrowB : qrowA;
    u16* dst = &AO[(b * S_LEN + qrow) * FEAT + h * HDIM + lk * 4];
#pragma unroll
    for (int nd = 0; nd < 4; ++nd) {
      us4 o;
      o.x = f2bf(oacc[nd][0] * inv);
      o.y = f2bf(oacc[nd][1] * inv);
      o.z = f2bf(oacc[nd][2] * inv);
      o.w = f2bf(oacc[nd][3] * inv);
      *(us4*)(dst + nd * 16) = o;
    }
  }
}

extern "C" void kernel_launch(void* const* d_in, const int* in_sizes, int n_in,
                              void* d_out, int out_size, void* d_ws, size_t ws_size,
                              hipStream_t stream) {
  const float* kv = (const float*)d_in[0];
  const float* q  = (const float*)d_in[1];
  const float* Wq = (const float*)d_in[2];
  const float* Wk = (const float*)d_in[3];
  const float* Wv = (const float*)d_in[4];
  const float* Wo = (const float*)d_in[5];

  float* emb = (float*)d_ws;                              // 512 KB
  u16* qbf  = (u16*)((char*)d_ws + S_LEN * HDIM * 4);
  u16* kvbf = qbf + NROWS * FEAT;                         // 8 MB each
  u16* WqT  = kvbf + NROWS * FEAT;
  u16* WkT  = WqT + FEAT * FEAT;                          // 2 MB each
  u16* WvT  = WkT + FEAT * FEAT;
  u16* WoT  = WvT + FEAT * FEAT;
  u16* Qb   = WoT + FEAT * FEAT;                          // 8 MB each
  u16* Kx   = Qb + NROWS * FEAT;
  u16* Vx   = Kx + NROWS * FEAT;
  u16* AO   = Vx + NROWS * FEAT;

  emb_kernel<<<(S_LEN * HDIM + 255) / 256, 256, 0, stream>>>(emb);
  convert_bf16<<<(NROWS * FEAT / 4 + 255) / 256, 256, 0, stream>>>(q, qbf, NROWS * FEAT / 4);
  convert_bf16<<<(NROWS * FEAT / 4 + 255) / 256, 256, 0, stream>>>(kv, kvbf, NROWS * FEAT / 4);
  wtrans<<<dim3(32, 32, 4), 256, 0, stream>>>(Wq, Wk, Wv, Wo, WqT, WkT, WvT, WoT);

  dim3 gg(NROWS / 128, FEAT / 128);  // (32, 8)
  gemm_bf16<0><<<gg, 256, 0, stream>>>(qbf, WqT, Qb, emb);
  gemm_bf16<1><<<gg, 256, 0, stream>>>(kvbf, WkT, Kx, emb);
  gemm_bf16<2><<<gg, 256, 0, stream>>>(kvbf, WvT, Vx, emb);

  attn_kernel<<<512, 256, 0, stream>>>(Qb, Kx, Vx, AO);

  gemm_bf16<3><<<gg, 256, 0, stream>>>(AO, WoT, d_out, emb);
}

// Round 4
// 146.906 us; speedup vs baseline: 3.1411x; 1.2251x over previous
//
#include <hip/hip_runtime.h>

typedef unsigned short u16;
typedef unsigned int u32;

#define S_LEN 2048
#define FEAT 1024
#define NHEAD 16
#define HDIM 64
#define NBATCH 2
#define NROWS (NBATCH * S_LEN)  // 4096

typedef float f32x4 __attribute__((ext_vector_type(4)));
typedef short s16x8 __attribute__((ext_vector_type(8)));
typedef u32 u32x2 __attribute__((ext_vector_type(2)));

#define LOG2E 1.4426950408889634f

__device__ inline u16 f2bf(float f) {
  u32 u = __float_as_uint(f);
  return (u16)((u + 0x7fffu + ((u >> 16) & 1u)) >> 16);
}

__device__ inline u32 cvt_pk_bf16(float lo, float hi) {
  u32 r;
  asm("v_cvt_pk_bf16_f32 %0, %1, %2" : "=v"(r) : "v"(lo), "v"(hi));
  return r;
}

__device__ inline float fexp2(float x) { return __builtin_amdgcn_exp2f(x); }

__device__ inline f32x4 mfma16(s16x8 a, s16x8 b, f32x4 c) {
  return __builtin_amdgcn_mfma_f32_16x16x32_bf16(a, b, c, 0, 0, 0);
}

typedef __attribute__((address_space(1))) void gvoid;
typedef __attribute__((address_space(3))) void lvoid;
__device__ inline void gload_lds16(const void* g, void* l) {
  __builtin_amdgcn_global_load_lds((gvoid*)g, (lvoid*)l, 16, 0, 0);
}

// ---------------- emb table: module's unusual RoPE multiplier ----------------
__global__ void emb_kernel(float* __restrict__ emb) {
  int i = blockIdx.x * 256 + threadIdx.x;
  if (i >= S_LEN * HDIM) return;
  int p = i >> 6, d = i & 63, j = d & 31;
  float invf = exp2f(-13.287712379549449f * (float)j / 32.0f);
  float a1 = (float)p * invf;
  float v1 = (d < 32) ? sinf(a1) : cosf(a1);
  float e;
  if (p == 0) {
    e = v1;
  } else {
    float a2 = (float)(S_LEN - p) * invf;
    float v2 = (d < 32) ? sinf(a2) : cosf(a2);
    e = 0.5f * (v1 + v2);
  }
  emb[i] = e;
}

// ---------------- f32 -> bf16 convert: q then kv in one launch ----------------
struct us4 { u16 x, y, z, w; };
__global__ void convert_bf16_2(const float* __restrict__ in0, u16* __restrict__ out0,
                               const float* __restrict__ in1, u16* __restrict__ out1,
                               int n4each) {
  int i = blockIdx.x * 256 + threadIdx.x;
  const float* in = in0;
  u16* out = out0;
  if (i >= n4each) { i -= n4each; in = in1; out = out1; }
  if (i >= n4each) return;
  float4 v = ((const float4*)in)[i];
  us4 o;
  o.x = f2bf(v.x); o.y = f2bf(v.y); o.z = f2bf(v.z); o.w = f2bf(v.w);
  ((us4*)out)[i] = o;
}

// ---------------- weight transpose + convert: Wt[o][i] = bf16(W[i][o]) ----------------
__global__ void wtrans(const float* __restrict__ w0, const float* __restrict__ w1,
                       const float* __restrict__ w2, const float* __restrict__ w3,
                       u16* __restrict__ o0, u16* __restrict__ o1,
                       u16* __restrict__ o2, u16* __restrict__ o3) {
  const float* W = blockIdx.z == 0 ? w0 : blockIdx.z == 1 ? w1 : blockIdx.z == 2 ? w2 : w3;
  u16* O = blockIdx.z == 0 ? o0 : blockIdx.z == 1 ? o1 : blockIdx.z == 2 ? o2 : o3;
  __shared__ float tile[32][33];
  int tx = threadIdx.x & 31, ty = threadIdx.x >> 5;  // 256 threads: 32 x 8
  int bi = blockIdx.x * 32, bo = blockIdx.y * 32;
#pragma unroll
  for (int r = 0; r < 32; r += 8) tile[ty + r][tx] = W[(bi + ty + r) * FEAT + bo + tx];
  __syncthreads();
#pragma unroll
  for (int r = 0; r < 32; r += 8) O[(bo + ty + r) * FEAT + bi + tx] = f2bf(tile[tx][ty + r]);
}

// ---------------- fused QKV projection GEMM ----------------
// 128x128 tiles, BK=32, 4 waves. blockIdx.y in [0,24): mode = y>>3 (0=Q,1=K,2=V),
// col0 = (y&7)*128. 768 blocks = 3/CU -> barrier stalls overlap across blocks.
// Q: out bf16 [b,h,s,d] *= emb*0.125; K: [b,h,s,d] *= emb; V: [b,h,d,s].
__global__ __launch_bounds__(256, 3) void gemm_qkv(
    const u16* __restrict__ qbf, const u16* __restrict__ kvbf,
    const u16* __restrict__ WqT, const u16* __restrict__ WkT, const u16* __restrict__ WvT,
    u16* __restrict__ Qb, u16* __restrict__ Kx, u16* __restrict__ Vx,
    const float* __restrict__ emb) {
  __shared__ __align__(16) u16 lA[2][128 * 32];
  __shared__ __align__(16) u16 lB[2][128 * 32];
  const int K = FEAT;
  int t = threadIdx.x;
  int w = t >> 6, l = t & 63;
  int lr = l & 15, lk = l >> 4;
  int mode = blockIdx.y >> 3;
  int row0 = blockIdx.x * 128, col0 = (blockIdx.y & 7) * 128;
  int wm = w >> 1, wn = w & 1;

  const u16* A = mode == 0 ? qbf : kvbf;
  const u16* Bt = mode == 0 ? WqT : mode == 1 ? WkT : WvT;
  u16* Out = mode == 0 ? Qb : mode == 1 ? Kx : Vx;

  f32x4 acc[4][4] = {};

  const u16* Asrc = A + (row0 + (t >> 2)) * K + (t & 3) * 8;
  const u16* Bsrc = Bt + (col0 + (t >> 2)) * K + (t & 3) * 8;

  auto stage = [&](int buf, int kt) {
    const u16* a = Asrc + kt * 32;
    const u16* b = Bsrc + kt * 32;
    gload_lds16(a,          &lA[buf][w * 512]);
    gload_lds16(a + 64 * K, &lA[buf][2048 + w * 512]);
    gload_lds16(b,          &lB[buf][w * 512]);
    gload_lds16(b + 64 * K, &lB[buf][2048 + w * 512]);
  };

  stage(0, 0);
  const int NK = K / 32;
  for (int kt = 0; kt < NK; ++kt) {
    __syncthreads();
    if (kt + 1 < NK) stage((kt + 1) & 1, kt + 1);
    int buf = kt & 1;
    s16x8 af[4], bfr[4];
#pragma unroll
    for (int mi = 0; mi < 4; ++mi)
      af[mi] = *(const s16x8*)&lA[buf][(wm * 64 + mi * 16 + lr) * 32 + lk * 8];
#pragma unroll
    for (int ni = 0; ni < 4; ++ni)
      bfr[ni] = *(const s16x8*)&lB[buf][(wn * 64 + ni * 16 + lr) * 32 + lk * 8];
#pragma unroll
    for (int mi = 0; mi < 4; ++mi)
#pragma unroll
      for (int ni = 0; ni < 4; ++ni)
        acc[mi][ni] = mfma16(af[mi], bfr[ni], acc[mi][ni]);
  }

  int rb = row0 + wm * 64 + lk * 4;
  int cb = col0 + wn * 64 + lr;
#pragma unroll
  for (int mi = 0; mi < 4; ++mi)
#pragma unroll
    for (int ni = 0; ni < 4; ++ni)
#pragma unroll
      for (int r = 0; r < 4; ++r) {
        int row = rb + mi * 16 + r;   // C/D layout: row=(l>>4)*4+r, col=l&15 [m89]
        int col = cb + ni * 16;
        float v = acc[mi][ni][r];
        int b = row >> 11, s = row & (S_LEN - 1);
        int h = col >> 6, d = col & (HDIM - 1);
        if (mode <= 1) {
          v *= emb[s * HDIM + d];
          if (mode == 0) v *= 0.125f;  // fold 1/sqrt(HD) into Q
          Out[(((b << 4) + h) * S_LEN + s) * HDIM + d] = f2bf(v);
        } else {
          Out[(((b << 4) + h) * HDIM + d) * S_LEN + s] = f2bf(v);
        }
      }
}

// ---------------- O-projection GEMM (f32 out) ----------------
__global__ __launch_bounds__(256, 3) void gemm_oproj(
    const u16* __restrict__ A, const u16* __restrict__ Bt, float* __restrict__ Out) {
  __shared__ __align__(16) u16 lA[2][128 * 32];
  __shared__ __align__(16) u16 lB[2][128 * 32];
  const int K = FEAT, N = FEAT;
  int t = threadIdx.x;
  int w = t >> 6, l = t & 63;
  int lr = l & 15, lk = l >> 4;
  int row0 = blockIdx.x * 128, col0 = blockIdx.y * 128;
  int wm = w >> 1, wn = w & 1;

  f32x4 acc[4][4] = {};

  const u16* Asrc = A + (row0 + (t >> 2)) * K + (t & 3) * 8;
  const u16* Bsrc = Bt + (col0 + (t >> 2)) * K + (t & 3) * 8;

  auto stage = [&](int buf, int kt) {
    const u16* a = Asrc + kt * 32;
    const u16* b = Bsrc + kt * 32;
    gload_lds16(a,          &lA[buf][w * 512]);
    gload_lds16(a + 64 * K, &lA[buf][2048 + w * 512]);
    gload_lds16(b,          &lB[buf][w * 512]);
    gload_lds16(b + 64 * K, &lB[buf][2048 + w * 512]);
  };

  stage(0, 0);
  const int NK = K / 32;
  for (int kt = 0; kt < NK; ++kt) {
    __syncthreads();
    if (kt + 1 < NK) stage((kt + 1) & 1, kt + 1);
    int buf = kt & 1;
    s16x8 af[4], bfr[4];
#pragma unroll
    for (int mi = 0; mi < 4; ++mi)
      af[mi] = *(const s16x8*)&lA[buf][(wm * 64 + mi * 16 + lr) * 32 + lk * 8];
#pragma unroll
    for (int ni = 0; ni < 4; ++ni)
      bfr[ni] = *(const s16x8*)&lB[buf][(wn * 64 + ni * 16 + lr) * 32 + lk * 8];
#pragma unroll
    for (int mi = 0; mi < 4; ++mi)
#pragma unroll
      for (int ni = 0; ni < 4; ++ni)
        acc[mi][ni] = mfma16(af[mi], bfr[ni], acc[mi][ni]);
  }

  int rb = row0 + wm * 64 + lk * 4;
  int cb = col0 + wn * 64 + lr;
#pragma unroll
  for (int mi = 0; mi < 4; ++mi)
#pragma unroll
    for (int ni = 0; ni < 4; ++ni)
#pragma unroll
      for (int r = 0; r < 4; ++r)
        Out[(rb + mi * 16 + r) * N + cb + ni * 16] = acc[mi][ni][r];
}

// ---------------- flash attention v3: block-shared LDS K/V, dual-half pairs ----------------
__global__ __launch_bounds__(256, 2) void attn_kernel(
    const u16* __restrict__ Q, const u16* __restrict__ Kb,
    const u16* __restrict__ Vt, u16* __restrict__ AO) {
  __shared__ __align__(16) u16 lK[2][64 * 64];  // 16 KB: [buf][key][d] (swizzled)
  __shared__ __align__(16) u16 lV[2][64 * 64];  // 16 KB: [buf][d][key] (swizzled)
  __shared__ __align__(16) u16 lP[4][16 * 64];  // 8 KB: per-wave P^T (swizzled)

  int t = threadIdx.x, w = t >> 6, l = t & 63;
  int lr = l & 15, lk = l >> 4;
  int bid = blockIdx.x;
  int bh = bid >> 4, qbp = bid & 15;      // 32 bh x 16 pairs
  int qtA = qbp, qtB = 31 - qbp;          // 64-row q-block indices
  int ntA = qtA + 1, ntB = qtB + 1;       // 64-key tiles per half (ntA < ntB)
  const u16* Qp = Q + bh * (S_LEN * HDIM);
  const char* Kc = (const char*)(Kb + bh * (S_LEN * HDIM));
  const char* Vc = (const char*)(Vt + bh * (HDIM * S_LEN));
  int b = bh >> 4, h = bh & 15;
  int sw = (lr & 7) << 4;

  int P0 = w * 1024 + l * 16;
  int row0 = P0 >> 7;
  int srcK0 = P0 ^ ((row0 & 7) << 4);                          // K tile contiguous 8KB
  int srcV0 = row0 * 4096 + ((P0 & 127) ^ ((row0 & 7) << 4));  // V rows strided 4KB

  auto stage = [&](int buf, int kt) {
    gload_lds16(Kc + kt * 8192 + srcK0,          (char*)&lK[buf][0] + w * 1024);
    gload_lds16(Kc + kt * 8192 + srcK0 + 4096,   (char*)&lK[buf][0] + w * 1024 + 4096);
    gload_lds16(Vc + kt * 128 + srcV0,           (char*)&lV[buf][0] + w * 1024);
    gload_lds16(Vc + kt * 128 + srcV0 + 131072,  (char*)&lV[buf][0] + w * 1024 + 4096);
  };

  int qrowA = qtA * 64 + w * 16 + lr;
  int qrowB = qtB * 64 + w * 16 + lr;
  s16x8 qA0 = *(const s16x8*)&Qp[qrowA * HDIM + lk * 8];
  s16x8 qA1 = *(const s16x8*)&Qp[qrowA * HDIM + lk * 8 + 32];
  s16x8 qB0 = *(const s16x8*)&Qp[qrowB * HDIM + lk * 8];
  s16x8 qB1 = *(const s16x8*)&Qp[qrowB * HDIM + lk * 8 + 32];

  f32x4 oA[4] = {}, oB[4] = {};
  float mA = -3.0e38f, lsA = 0.f, mB = -3.0e38f, lsB = 0.f;
  char* plb = (char*)&lP[w][0];

  auto half_sm_pv = [&](f32x4 (&sacc)[4], f32x4 (&oacc)[4], float& m, float& ls,
                        int qrow, bool diag, int kt, const s16x8 (&vf)[4][2]) {
    if (diag) {
#pragma unroll
      for (int nb = 0; nb < 4; ++nb)
#pragma unroll
        for (int r = 0; r < 4; ++r)
          if (kt * 64 + nb * 16 + lk * 4 + r > qrow) sacc[nb][r] = -3.0e38f;
    }
    float tm = sacc[0][0];
#pragma unroll
    for (int nb = 0; nb < 4; ++nb)
#pragma unroll
      for (int r = 0; r < 4; ++r) tm = fmaxf(tm, sacc[nb][r]);
    tm = fmaxf(tm, __shfl_xor(tm, 16, 64));
    tm = fmaxf(tm, __shfl_xor(tm, 32, 64));
    if (!__all(tm <= m + 8.0f)) {  // defer-max (T13)
      float mn = fmaxf(m, tm);
      float fs = fexp2((m - mn) * LOG2E);
      m = mn;
      ls *= fs;
#pragma unroll
      for (int nd = 0; nd < 4; ++nd)
#pragma unroll
        for (int r = 0; r < 4; ++r) oacc[nd][r] *= fs;
    }
    float rs = 0.f;
    float p[4][4];
#pragma unroll
    for (int nb = 0; nb < 4; ++nb)
#pragma unroll
      for (int r = 0; r < 4; ++r) {
        float pv = fexp2((sacc[nb][r] - m) * LOG2E);
        p[nb][r] = pv;
        rs += pv;
      }
    rs += __shfl_xor(rs, 16, 64);
    rs += __shfl_xor(rs, 32, 64);
    ls += rs;
#pragma unroll
    for (int nb = 0; nb < 4; ++nb) {
      u32x2 pw;
      pw.x = cvt_pk_bf16(p[nb][0], p[nb][1]);
      pw.y = cvt_pk_bf16(p[nb][2], p[nb][3]);
      int off = (lr * 128 + nb * 32 + lk * 8) ^ sw;
      *(u32x2*)(plb + off) = pw;
    }
    asm volatile("s_waitcnt lgkmcnt(0)" ::: "memory");
    __builtin_amdgcn_sched_barrier(0);
    s16x8 pf0 = *(const s16x8*)(plb + ((lr * 128 + lk * 16) ^ sw));
    s16x8 pf1 = *(const s16x8*)(plb + ((lr * 128 + 64 + lk * 16) ^ sw));
    __builtin_amdgcn_s_setprio(1);
#pragma unroll
    for (int nd = 0; nd < 4; ++nd) {
      oacc[nd] = mfma16(vf[nd][0], pf0, oacc[nd]);
      oacc[nd] = mfma16(vf[nd][1], pf1, oacc[nd]);
    }
    __builtin_amdgcn_s_setprio(0);
  };

  stage(0, 0);
  for (int kt = 0; kt < ntB; ++kt) {
    __syncthreads();
    if (kt + 1 < ntB) stage((kt + 1) & 1, kt + 1);
    int buf = kt & 1;
    const char* kb = (const char*)&lK[buf][0];
    const char* vb = (const char*)&lV[buf][0];
    bool dual = (kt < ntA);

    s16x8 vf[4][2];
#pragma unroll
    for (int nd = 0; nd < 4; ++nd)
#pragma unroll
      for (int ks = 0; ks < 2; ++ks)
        vf[nd][ks] = *(const s16x8*)(vb + nd * 2048 + lr * 128 + ((lk * 16 + ks * 64) ^ sw));

    f32x4 sA[4] = {}, sB[4] = {};
    __builtin_amdgcn_s_setprio(1);
#pragma unroll
    for (int nb = 0; nb < 4; ++nb)
#pragma unroll
      for (int ks = 0; ks < 2; ++ks) {
        s16x8 kf = *(const s16x8*)(kb + nb * 2048 + lr * 128 + ((lk * 16 + ks * 64) ^ sw));
        sB[nb] = mfma16(kf, ks ? qB1 : qB0, sB[nb]);
        if (dual) sA[nb] = mfma16(kf, ks ? qA1 : qA0, sA[nb]);
      }
    __builtin_amdgcn_s_setprio(0);

    half_sm_pv(sB, oB, mB, lsB, qrowB, kt == ntB - 1, kt, vf);
    if (dual) half_sm_pv(sA, oA, mA, lsA, qrowA, kt == ntA - 1, kt, vf);
  }

#pragma unroll
  for (int half = 0; half < 2; ++half) {
    f32x4* oacc = half ? oB : oA;
    float inv = 1.0f / (half ? lsB : lsA);
    int qrow = half ? qrowB : qrowA;
    u16* dst = &AO[(b * S_LEN + qrow) * FEAT + h * HDIM + lk * 4];
#pragma unroll
    for (int nd = 0; nd < 4; ++nd) {
      us4 o;
      o.x = f2bf(oacc[nd][0] * inv);
      o.y = f2bf(oacc[nd][1] * inv);
      o.z = f2bf(oacc[nd][2] * inv);
      o.w = f2bf(oacc[nd][3] * inv);
      *(us4*)(dst + nd * 16) = o;
    }
  }
}

extern "C" void kernel_launch(void* const* d_in, const int* in_sizes, int n_in,
                              void* d_out, int out_size, void* d_ws, size_t ws_size,
                              hipStream_t stream) {
  const float* kv = (const float*)d_in[0];
  const float* q  = (const float*)d_in[1];
  const float* Wq = (const float*)d_in[2];
  const float* Wk = (const float*)d_in[3];
  const float* Wv = (const float*)d_in[4];
  const float* Wo = (const float*)d_in[5];

  float* emb = (float*)d_ws;                              // 512 KB
  u16* qbf  = (u16*)((char*)d_ws + S_LEN * HDIM * 4);
  u16* kvbf = qbf + NROWS * FEAT;                         // 8 MB each
  u16* WqT  = kvbf + NROWS * FEAT;
  u16* WkT  = WqT + FEAT * FEAT;                          // 2 MB each
  u16* WvT  = WkT + FEAT * FEAT;
  u16* WoT  = WvT + FEAT * FEAT;
  u16* Qb   = WoT + FEAT * FEAT;                          // 8 MB each
  u16* Kx   = Qb + NROWS * FEAT;
  u16* Vx   = Kx + NROWS * FEAT;
  u16* AO   = Vx + NROWS * FEAT;

  emb_kernel<<<(S_LEN * HDIM + 255) / 256, 256, 0, stream>>>(emb);
  convert_bf16_2<<<(2 * NROWS * FEAT / 4 + 255) / 256, 256, 0, stream>>>(
      q, qbf, kv, kvbf, NROWS * FEAT / 4);
  wtrans<<<dim3(32, 32, 4), 256, 0, stream>>>(Wq, Wk, Wv, Wo, WqT, WkT, WvT, WoT);

  gemm_qkv<<<dim3(NROWS / 128, 24), 256, 0, stream>>>(qbf, kvbf, WqT, WkT, WvT,
                                                      Qb, Kx, Vx, emb);

  attn_kernel<<<512, 256, 0, stream>>>(Qb, Kx, Vx, AO);

  gemm_oproj<<<dim3(NROWS / 128, FEAT / 128), 256, 0, stream>>>(AO, WoT, (float*)d_out);
}